// Round 1
// baseline (716.178 us; speedup 1.0000x reference)
//
#include <hip/hip_runtime.h>
#include <math.h>

#define TT 512
#define BB 512
#define FF 14
#define H1 32
#define H2 64
#define G1 128   // 4*H1
#define G2 256   // 4*H2

__device__ __forceinline__ float sigmoidf_(float x) {
    return 1.0f / (1.0f + __expf(-x));
}
__device__ __forceinline__ float tanhf_(float x) {
    // tanh via exp, numerically stable
    float e = __expf(-2.0f * fabsf(x));
    float t = (1.0f - e) / (1.0f + e);
    return copysignf(t, x);
}

// One block per batch row. 256 threads = 4 waves.
// Weights live in registers: thread t owns layer-2 gate o=t (96 weights),
// and (t<128) layer-1 gate o=t (46 weights). LDS holds only small state.
__global__ __launch_bounds__(256, 2) void lstm3_kernel(
    const float* __restrict__ x,
    const float* __restrict__ Wih1, const float* __restrict__ Whh1,
    const float* __restrict__ bih1, const float* __restrict__ bhh1,
    const float* __restrict__ Wih2, const float* __restrict__ Whh2,
    const float* __restrict__ bih2, const float* __restrict__ bhh2,
    const float* __restrict__ Wfc1, const float* __restrict__ bfc1,
    const float* __restrict__ Wfc2, const float* __restrict__ bfc2,
    const float* __restrict__ Wfc,  const float* __restrict__ bfc,
    float* __restrict__ out)
{
    const int row = blockIdx.x;
    const int t   = threadIdx.x;

    __shared__ float xbuf[16];     // current x_t (14 used)
    __shared__ float h1s[H1];
    __shared__ float h2s[H2];
    __shared__ float g1buf[G1];
    __shared__ float g2buf[G2];
    __shared__ float mlp1[8];
    __shared__ float mlp2[8];

    // ---- preload layer-2 weights (gate o = t) into registers ----
    float w2[H1 + H2];
    {
        const float* p = Wih2 + t * H1;
        #pragma unroll
        for (int k = 0; k < H1; ++k) w2[k] = p[k];
        const float* q = Whh2 + t * H2;
        #pragma unroll
        for (int k = 0; k < H2; ++k) w2[H1 + k] = q[k];
    }
    const float b2r = bih2[t] + bhh2[t];

    // ---- preload layer-1 weights (gate o = t, t<128) ----
    float w1[FF + H1];
    float b1r = 0.0f;
    if (t < G1) {
        const float* p = Wih1 + t * FF;
        #pragma unroll
        for (int k = 0; k < FF; ++k) w1[k] = p[k];
        const float* q = Whh1 + t * H1;
        #pragma unroll
        for (int k = 0; k < H1; ++k) w1[FF + k] = q[k];
        b1r = bih1[t] + bhh1[t];
    }

    float c1r = 0.0f;   // layer-1 cell state, owned by threads 0..31 (j = t)

    // ---- init state, stage x[0], prefetch x[1] ----
    if (t < H1) h1s[t] = 0.0f;
    if (t < H2) h2s[t] = 0.0f;
    float xreg = 0.0f;
    if (t >= 128 && t < 128 + FF) {
        const int f = t - 128;
        xbuf[f] = x[(size_t)0 * BB * FF + row * FF + f];
        xreg    = x[(size_t)1 * BB * FF + row * FF + f];
    }
    __syncthreads();

    for (int step = 0; step < TT; ++step) {
        // ---- layer-1 gates: threads 0..127, gate o = t ----
        if (t < G1) {
            float acc = b1r;
            #pragma unroll
            for (int f = 0; f < FF; ++f) acc = fmaf(xbuf[f], w1[f], acc);
            #pragma unroll
            for (int k = 0; k < H1; ++k) acc = fmaf(h1s[k], w1[FF + k], acc);
            g1buf[t] = acc;
        }
        __syncthreads();

        // ---- h1/c1 update (threads 0..31); x staging (threads 128..141) ----
        if (t < H1) {
            const float ig = g1buf[t];
            const float fg = g1buf[t + 32];
            const float gg = g1buf[t + 64];
            const float og = g1buf[t + 96];
            const float cn = sigmoidf_(fg) * c1r + sigmoidf_(ig) * tanhf_(gg);
            c1r = cn;
            h1s[t] = sigmoidf_(og) * tanhf_(cn);
        } else if (t >= 128 && t < 128 + FF) {
            const int f = t - 128;
            xbuf[f] = xreg;  // x[step+1]
            const int tn = (step + 2 < TT) ? (step + 2) : (TT - 1);
            xreg = x[(size_t)tn * BB * FF + row * FF + f];
        }
        __syncthreads();

        // ---- layer-2 gates: all 256 threads, gate o = t ----
        {
            float a = b2r;
            #pragma unroll
            for (int k = 0; k < H1; ++k) a = fmaf(h1s[k], w2[k], a);
            #pragma unroll
            for (int k = 0; k < H2; ++k) a = fmaf(h2s[k], w2[H1 + k], a);
            g2buf[t] = a;
        }
        __syncthreads();

        // ---- h2 update (threads 0..63). Layer-2 cell is always 0 in ref. ----
        if (t < H2) {
            const float ig = g2buf[t];
            const float gg = g2buf[t + 128];
            const float og = g2buf[t + 192];
            const float cn = sigmoidf_(ig) * tanhf_(gg);
            h2s[t] = sigmoidf_(og) * tanhf_(cn);
        }
        __syncthreads();
    }

    // ---- MLP head: relu(h2) -> fc1(8)+relu -> fc2(8)+relu -> fc(1) ----
    if (t < 8) {
        float a = bfc1[t];
        #pragma unroll
        for (int k = 0; k < H2; ++k)
            a = fmaf(fmaxf(h2s[k], 0.0f), Wfc1[t * H2 + k], a);
        mlp1[t] = fmaxf(a, 0.0f);
    }
    __syncthreads();
    if (t < 8) {
        float a = bfc2[t];
        #pragma unroll
        for (int k = 0; k < 8; ++k) a = fmaf(mlp1[k], Wfc2[t * 8 + k], a);
        mlp2[t] = fmaxf(a, 0.0f);
    }
    __syncthreads();
    if (t == 0) {
        float a = bfc[0];
        #pragma unroll
        for (int k = 0; k < 8; ++k) a = fmaf(mlp2[k], Wfc[k], a);
        out[row] = a;
    }
}

extern "C" void kernel_launch(void* const* d_in, const int* in_sizes, int n_in,
                              void* d_out, int out_size, void* d_ws, size_t ws_size,
                              hipStream_t stream) {
    const float* x    = (const float*)d_in[0];
    const float* Wih1 = (const float*)d_in[1];
    const float* Whh1 = (const float*)d_in[2];
    const float* bih1 = (const float*)d_in[3];
    const float* bhh1 = (const float*)d_in[4];
    const float* Wih2 = (const float*)d_in[5];
    const float* Whh2 = (const float*)d_in[6];
    const float* bih2 = (const float*)d_in[7];
    const float* bhh2 = (const float*)d_in[8];
    const float* Wfc1 = (const float*)d_in[9];
    const float* bfc1 = (const float*)d_in[10];
    const float* Wfc2 = (const float*)d_in[11];
    const float* bfc2 = (const float*)d_in[12];
    const float* Wfc  = (const float*)d_in[13];
    const float* bfc  = (const float*)d_in[14];
    float* out = (float*)d_out;

    lstm3_kernel<<<dim3(BB), dim3(256), 0, stream>>>(
        x, Wih1, Whh1, bih1, bhh1, Wih2, Whh2, bih2, bhh2,
        Wfc1, bfc1, Wfc2, bfc2, Wfc, bfc, out);
}